// Round 3
// baseline (145.465 us; speedup 1.0000x reference)
//
#include <hip/hip_runtime.h>

// rmsdLoss via associative affine scan — R13.
// R12 (quat scan) regressed 43.6->63.3us: allocator targeted the 64-VGPR
// occupancy tier and spilled the tl[8][3] snapshot arrays (WRITE_SIZE 64B ->
// 65.6MB = 128B/thread scratch; FETCH +25MB read-back; +20us = the scratch
// round-trip at ~6TB/s). The quat algebra itself passed (absmax 0).
// R13 keeps the 4+3-float quat scan but STREAMS per-step local translations
// to LDS during the chunk compose (fire-and-forget, off the serial chain) so
// only the running (q,t) = 7 floats crosses the scan. Peak pressure ~55 VGPR
// -> no spill at the 64-reg tier. Epilogue: each wave reads back its OWN raw
// tl slots (same-thread RAW, lgkmcnt-ordered, no barrier), applies its G,
// writes transformed in place; one barrier; targ waves diff both arenas and
// issue per-wave atomics (2/block, 'part' relay + 3rd barrier dropped).
// LDS 13->26KB (still 6 blocks/CU); pitch 25 -> 2-way bank alias = free.
//
// Geometry (R11): chain split across 128 lanes (2 waves/chain, CHUNK=8);
// block = 256 thr = 4 waves (wv0,1 = pred halves, wv2,3 = targ halves); each
// lane loads its own 33 contiguous dwords. Quat build (R12, verified): step
// rot = Rx(beta)Rz(alpha), quat direct from half-angle sqrts; translations
// decouple into commutative 3-float sum scan after one rotate by q_excl.

#define LROW  4087
#define NSTEP 1021
#define NROW  2048
#define CHUNK 8
#define PITCH 25
#define EPSF  1e-6f
#define INVMEAN (1.0f / (2048.0f * 1024.0f * 3.0f))

__device__ __forceinline__ float frcp(float x){ return __builtin_amdgcn_rcpf(x); }

struct Q { float w, x, y, z; };

__device__ __forceinline__ Q qmul(const Q a, const Q b){
  Q c;
  c.w = a.w*b.w - a.x*b.x - a.y*b.y - a.z*b.z;
  c.x = a.w*b.x + a.x*b.w + a.y*b.z - a.z*b.y;
  c.y = a.w*b.y - a.x*b.z + a.y*b.w + a.z*b.x;
  c.z = a.w*b.z + a.x*b.y - a.y*b.x + a.z*b.w;
  return c;
}

// rotate v by unit quat q: v' = v + 2*(u x (u x v + w v)), u=(x,y,z)
__device__ __forceinline__ void qrot(const Q q, float vx, float vy, float vz,
                                     float& rx, float& ry, float& rz){
  const float cx = q.y*vz - q.z*vy + q.w*vx;
  const float cy = q.z*vx - q.x*vz + q.w*vy;
  const float cz = q.x*vy - q.y*vx + q.w*vz;
  rx = fmaf(2.f, q.y*cz - q.z*cy, vx);
  ry = fmaf(2.f, q.z*cx - q.x*cz, vy);
  rz = fmaf(2.f, q.x*cy - q.y*cx, vz);
}

__global__ void __launch_bounds__(256, 4)
rmsd_kernel(const float* __restrict__ pred, const float* __restrict__ targ,
            float* __restrict__ out){
  __shared__ float pos[2][128*PITCH];  // 25.6 KB: raw local tl, then positions
  __shared__ float Tbuf[2][8];         // per-chain half-0 totals: q, t
  __shared__ float ini[3];             // pred a1x, a2x, a2y

  const int row  = blockIdx.x;
  const int tid  = threadIdx.x;
  const int ln   = tid & 63;
  const int wv   = tid >> 6;          // 0..3
  const int c    = wv >> 1;           // 0 = pred, 1 = targ
  const int half = wv & 1;            // which half of the chain
  const int lid  = (half << 6) | ln;  // 0..127 lane-in-chain
  const int j0   = lid * CHUNK;       // first step owned (<= 1016)

  const float* __restrict__ v = (c ? targ : pred) + (size_t)row * LROW;
  const float cl = c ? 1e30f : 1.0f;  // reference clips pred only
  float* __restrict__ slot = &pos[c][lid * PITCH];

  // broadcast fold inputs (wave-uniform -> scalar loads)
  const float rb0 = fminf(fmaxf(v[3064], -cl), cl);
  const float rd0 = fminf(fmaxf(v[2042], -cl), cl);
  const float rb1 = fminf(fmaxf(v[3065], -cl), cl);

  // ---- batch per-lane loads: 33 contiguous dwords, all independent ----
  float s0[CHUNK], s1[CHUNK], dd[CHUNK], bv[CHUNK+1];
  #pragma unroll
  for (int k = 0; k < CHUNK; ++k){
    s0[k] = v[2*(j0+k)];
    s1[k] = v[2*(j0+k)+1];
    dd[k] = v[2043 + j0 + k];
  }
  #pragma unroll
  for (int m = 0; m <= CHUNK; ++m){
    int ix = 3065 + j0 + m;
    if (ix > 4086) ix = 4086;        // tail lane clamp (garbage steps unused)
    bv[m] = v[ix];
  }
  #pragma unroll
  for (int m = 0; m <= CHUNK; ++m)
    bv[m] = fmaf(fminf(fmaxf(bv[m], -cl), cl), 1.05f, 1.95f);

  // ---- per-step P + step quat (R11-style small loop; arrays die below) ----
  float Px[CHUNK], Py[CHUNK], Pz[CHUNK];
  float qw[CHUNK], qx[CHUNK], qy[CHUNK], qz[CHUNK];
  #pragma unroll
  for (int k = 0; k < CHUNK; ++k){
    const float a0 = fminf(fmaxf(s0[k], -cl), cl);
    const float a1 = fminf(fmaxf(s1[k], -cl), cl);
    const float d  = fmaf(fminf(fmaxf(dd[k], -cl), cl), 1.75f, 3.25f);
    const float b1 = bv[k], b2 = bv[k+1];
    float ct = (b1*b1 + b2*b2 - d*d) * frcp(2.0f*b1*b2);
    ct = fminf(fmaxf(ct, -1.0f + EPSF), 1.0f - EPSF);
    const float st = sqrtf(fmaxf(1.0f - ct*ct, 0.0f));
    const float r2 = a0*a0 + a1*a1;
    const bool ok = r2 > 1e-36f;
    const float ir = ok ? frcp(sqrtf(r2)) : 0.0f;
    const float scv = a0 * ir;                 // sin(chi)
    const float ccv = ok ? a1 * ir : 1.0f;     // cos(chi)
    const float bst = b2 * st;
    Px[k] = -b2*ct; Py[k] = bst*ccv; Pz[k] = bst*scv;
    // step quat = qx(beta) x qz(alpha); cos a=-ct, sin a=st; cos b=ccv, sin b=scv
    const float ca2 = sqrtf(0.5f*(1.0f - ct));                 // cos(a/2)
    const float sa2 = sqrtf(0.5f*(1.0f + ct));                 // sin(a/2)
    const float cb2 = sqrtf(fmaxf(0.5f*(1.0f + ccv), 0.0f));   // cos(b/2)
    const float sb2 = __builtin_copysignf(
                        sqrtf(fmaxf(0.5f*(1.0f - ccv), 0.0f)), scv); // sin(b/2)
    qw[k] = cb2*ca2; qx[k] = sb2*ca2; qy[k] = -sb2*sa2; qz[k] = cb2*sa2;
  }

  // ---- local chunk compose: running (q,t) only; stream tl[k] to LDS ----
  Q q; q.w = qw[0]; q.x = qx[0]; q.y = qy[0]; q.z = qz[0];
  float tx = Px[0], ty = Py[0], tz = Pz[0];
  slot[0] = tx; slot[1] = ty; slot[2] = tz;
  #pragma unroll
  for (int k = 1; k < CHUNK; ++k){
    float rx, ry, rz;
    qrot(q, Px[k], Py[k], Pz[k], rx, ry, rz);
    tx += rx; ty += ry; tz += rz;
    slot[3*k] = tx; slot[3*k+1] = ty; slot[3*k+2] = tz;
    Q qs; qs.w = qw[k]; qs.x = qx[k]; qs.y = qy[k]; qs.z = qz[k];
    q = qmul(q, qs);
  }

  // ---- in-wave inclusive quat scan (Hillis-Steele, non-commutative) ----
  #pragma unroll
  for (int off = 1; off < 64; off <<= 1){
    Q o;
    o.w = __shfl_up(q.w, off); o.x = __shfl_up(q.x, off);
    o.y = __shfl_up(q.y, off); o.z = __shfl_up(q.z, off);
    const bool pr = (ln >= off);
    o.w = pr ? o.w : 1.0f; o.x = pr ? o.x : 0.0f;
    o.y = pr ? o.y : 0.0f; o.z = pr ? o.z : 0.0f;
    q = qmul(o, q);                      // earlier lanes applied first
  }

  // exclusive quat prefix
  Q qe;
  qe.w = __shfl_up(q.w, 1); qe.x = __shfl_up(q.x, 1);
  qe.y = __shfl_up(q.y, 1); qe.z = __shfl_up(q.z, 1);
  if (ln == 0){ qe.w = 1.0f; qe.x = 0.0f; qe.y = 0.0f; qe.z = 0.0f; }

  // ---- translation: w = R_excl * t_chunk, then commutative 3-float scan ----
  float wx, wy, wz;
  qrot(qe, tx, ty, tz, wx, wy, wz);
  float sx = wx, sy = wy, sz = wz;
  #pragma unroll
  for (int off = 1; off < 64; off <<= 1){
    const float ax = __shfl_up(sx, off);
    const float ay = __shfl_up(sy, off);
    const float az = __shfl_up(sz, off);
    if (ln >= off){ sx += ax; sy += ay; sz += az; }
  }
  float tex = sx - wx, tey = sy - wy, tez = sz - wz;   // exclusive prefix

  // half-0 publishes chain-half totals (lane 63 inclusive)
  if (half == 0 && ln == 63){
    Tbuf[c][0] = q.w; Tbuf[c][1] = q.x; Tbuf[c][2] = q.y; Tbuf[c][3] = q.z;
    Tbuf[c][4] = sx;  Tbuf[c][5] = sy;  Tbuf[c][6] = sz;
  }
  __syncthreads();

  if (half == 1){    // prepend half-0 total: E = T o E_local
    Q T; T.w = Tbuf[c][0]; T.x = Tbuf[c][1]; T.y = Tbuf[c][2]; T.z = Tbuf[c][3];
    float rx, ry, rz;
    qrot(T, tex, tey, tez, rx, ry, rz);
    tex = Tbuf[c][4] + rx; tey = Tbuf[c][5] + ry; tez = Tbuf[c][6] + rz;
    qe = qmul(T, qe);
  }

  // ---- fold (F0, a2): G.M = F0 * R(qe), G.t = a2 + F0 * te ----
  const float bl0 = fmaf(rb0, 1.05f, 1.95f);
  const float d0  = fmaf(rd0, 1.75f, 3.25f);
  const float b1f = fmaf(rb1, 1.05f, 1.95f);
  float ct0 = (bl0*bl0 + b1f*b1f - d0*d0) * frcp(2.0f*bl0*b1f);
  ct0 = fminf(fmaxf(ct0, -1.0f + EPSF), 1.0f - EPSF);
  const float st0 = sqrtf(fmaxf(1.0f - ct0*ct0, 0.0f));
  const float a1x = bl0;
  const float a2x = bl0 - b1f*ct0;
  const float a2y = b1f*st0;

  // qF = Rz(g), cos g = -ct0, sin g = st0; qG = qF x qe
  const float cg2 = sqrtf(0.5f*(1.0f - ct0));
  const float sg2 = sqrtf(0.5f*(1.0f + ct0));
  Q g;
  g.w = cg2*qe.w - sg2*qe.z;
  g.x = cg2*qe.x - sg2*qe.y;
  g.y = cg2*qe.y + sg2*qe.x;
  g.z = cg2*qe.z + sg2*qe.w;

  const float gtx = a2x + (-ct0*tex - st0*tey);
  const float gty = a2y + ( st0*tex - ct0*tey);
  const float gtz = tez;

  // quat -> matrix with s = 2/|q|^2 (absorbs scan drift, no sqrt)
  const float nrm = g.w*g.w + g.x*g.x + g.y*g.y + g.z*g.z;
  const float s2n = 2.0f * frcp(nrm);
  const float xs = g.x*s2n, ys = g.y*s2n, zs = g.z*s2n;
  const float wxm = g.w*xs, wym = g.w*ys, wzm = g.w*zs;
  const float xxm = g.x*xs, xym = g.x*ys, xzm = g.x*zs;
  const float yym = g.y*ys, yzm = g.y*zs, zzm = g.z*zs;
  const float m00 = 1.0f-(yym+zzm), m01 = xym-wzm,        m02 = xzm+wym;
  const float m10 = xym+wzm,        m11 = 1.0f-(xxm+zzm), m12 = yzm-wxm;
  const float m20 = xzm-wym,        m21 = yzm+wxm,        m22 = 1.0f-(xxm+yym);

  // ---- transform own slots in place: p_k = G.t + G.M * tl[k] ----
  // (same-thread RAW on own LDS slots: compiler orders via lgkmcnt)
  #pragma unroll
  for (int k = 0; k < CHUNK; ++k){
    const float px = slot[3*k], py = slot[3*k+1], pz = slot[3*k+2];
    slot[3*k]   = gtx + m00*px + m01*py + m02*pz;
    slot[3*k+1] = gty + m10*px + m11*py + m12*pz;
    slot[3*k+2] = gtz + m20*px + m21*py + m22*pz;
  }
  if (c == 0 && lid == 0){ ini[0] = a1x; ini[1] = a2x; ini[2] = a2y; }
  __syncthreads();

  // ---- targ waves: diff both arenas + reduce; 2 atomics/block ----
  if (c == 1){
    float acc = 0.0f;
    if (lid == 0){
      const float dx = ini[0] - a1x;   // a1 differs only in x; a0 diff = 0
      const float dy = ini[1] - a2x;   // a2 differs in x,y (z = 0)
      const float dz = ini[2] - a2y;
      acc = dx*dx + dy*dy + dz*dz;
    }
    const float* __restrict__ ppos = &pos[0][lid * PITCH];
    #pragma unroll
    for (int k = 0; k < CHUNK; ++k){
      if (j0 + k < NSTEP){
        const float dx = ppos[3*k]   - slot[3*k];
        const float dy = ppos[3*k+1] - slot[3*k+1];
        const float dz = ppos[3*k+2] - slot[3*k+2];
        acc = fmaf(dx, dx, acc);
        acc = fmaf(dy, dy, acc);
        acc = fmaf(dz, dz, acc);
      }
    }
    #pragma unroll
    for (int off = 32; off > 0; off >>= 1) acc += __shfl_down(acc, off);
    if (ln == 0) atomicAdd(out, acc * INVMEAN);
  }
}

extern "C" void kernel_launch(void* const* d_in, const int* in_sizes, int n_in,
                              void* d_out, int out_size, void* d_ws, size_t ws_size,
                              hipStream_t stream) {
  const float* pred = (const float*)d_in[0];
  const float* targ = (const float*)d_in[1];
  float* out = (float*)d_out;

  hipMemsetAsync(d_out, 0, sizeof(float), stream);
  rmsd_kernel<<<NROW, 256, 0, stream>>>(pred, targ, out);
}

// Round 4
// 117.929 us; speedup vs baseline: 1.2335x; 1.2335x over previous
//
#include <hip/hip_runtime.h>

// rmsdLoss via associative affine scan — R14.
// R12/R13 post-mortem: quaternion scan is a net loss at CHUNK=8 (qrot+qmul+
// half-angle build ~114 issue-cy/step vs matrix xstepP ~84; scan-level savings
// ~320cy eaten by 8x30 compose extras, R13 added LDS RMW waits on top).
// Reverted to R11's matrix scan (proven 43.6us, no spills).
// R14 theory: R11 is load-serialization-limited, not VALU-limited. Each thread
// needs 33 loaded floats live at once but the allocator's 48-VGPR tier forces
// the batch into several waitcnt-separated groups -> 3-6 serialized ~500cy L3
// round-trips/thread (VALUBusy 44%, stalls 56%). Fix:
//  1) register headroom: __launch_bounds__(256) + amdgpu_waves_per_eu(2,4)
//     (cap 128 VGPR; measured residency ~2.75 waves/SIMD anyway, so a
//     4-wave register tier can't hurt observed occupancy);
//  2) vectorized loads: 33 scalar -> 9 dwordx4-class (sc 4, d13 2, bl 2+1;
//     4B-aligned ext_vector since rows are odd-strided; lane-127 tail clamp
//     via 2 cndmask, needs only bv[0..5] which stay exact).
// Geometry unchanged (R11): chain split across 128 lanes (2 waves/chain,
// CHUNK=8); block = 256 thr = 4 waves (wv0,1 pred halves, wv2,3 targ halves);
// 12-float affine Hillis-Steele in-wave scan + 1 cross-wave level via LDS.

#define LROW  4087
#define NSTEP 1021
#define NROW  2048
#define CHUNK 8
#define EPSF  1e-6f
#define INVMEAN (1.0f / (2048.0f * 1024.0f * 3.0f))

typedef float f4 __attribute__((ext_vector_type(4), aligned(4)));

__device__ __forceinline__ float frcp(float x){ return __builtin_amdgcn_rcpf(x); }
__device__ __forceinline__ float frsq(float x){ return __builtin_amdgcn_rsqf(x); }

struct Xf { float f[12]; };  // COLUMN-major: f[0..2]=c0, f[3..5]=c1, f[6..8]=c2, f[9..11]=t

__device__ __forceinline__ Xf xident(){
  Xf X;
  X.f[0]=1.f; X.f[1]=0.f; X.f[2]=0.f;
  X.f[3]=0.f; X.f[4]=1.f; X.f[5]=0.f;
  X.f[6]=0.f; X.f[7]=0.f; X.f[8]=1.f;
  X.f[9]=0.f; X.f[10]=0.f; X.f[11]=0.f;
  return X;
}

// A applied first, then B: C.M = A.M*B.M (columns), C.t = A.t + A.M*B.t
__device__ __forceinline__ Xf xcombine(const Xf& A, const Xf& B){
  Xf C;
  #pragma unroll
  for (int c3 = 0; c3 < 12; c3 += 3){
    const float bx = B.f[c3], by = B.f[c3+1], bz = B.f[c3+2];
    C.f[c3]   = A.f[0]*bx + A.f[3]*by + A.f[6]*bz;
    C.f[c3+1] = A.f[1]*bx + A.f[4]*by + A.f[7]*bz;
    C.f[c3+2] = A.f[2]*bx + A.f[5]*by + A.f[8]*bz;
  }
  C.f[9] += A.f[9]; C.f[10] += A.f[10]; C.f[11] += A.f[11];
  return C;
}

__device__ __forceinline__ void xstepP(Xf& X, float Px, float Py, float Pz){
  const float l2 = Px*Px + Py*Py + Pz*Pz;
  const float q  = frsq(l2);
  const float hx = q*Px, hy = q*Py, hz = q*Pz;
  const float ist = frsq(fmaxf(hy*hy + hz*hz, 1e-12f));   // 1/st, cancellation-free
  const float ux = X.f[0]*Px + X.f[3]*Py + X.f[6]*Pz;
  const float uy = X.f[1]*Px + X.f[4]*Py + X.f[7]*Pz;
  const float uz = X.f[2]*Px + X.f[5]*Py + X.f[8]*Pz;
  X.f[9] += ux; X.f[10] += uy; X.f[11] += uz;
  const float n0x = q*ux, n0y = q*uy, n0z = q*uz;
  const float n1x = ist*(hx*n0x - X.f[0]);
  const float n1y = ist*(hx*n0y - X.f[1]);
  const float n1z = ist*(hx*n0z - X.f[2]);
  const float n2x = ist*(hy*X.f[6] - hz*X.f[3]);
  const float n2y = ist*(hy*X.f[7] - hz*X.f[4]);
  const float n2z = ist*(hy*X.f[8] - hz*X.f[5]);
  X.f[0]=n0x; X.f[1]=n0y; X.f[2]=n0z;
  X.f[3]=n1x; X.f[4]=n1y; X.f[5]=n1z;
  X.f[6]=n2x; X.f[7]=n2y; X.f[8]=n2z;
}

__device__ __forceinline__ void xinitP(Xf& X, float Px, float Py, float Pz){
  const float l2 = Px*Px + Py*Py + Pz*Pz;
  const float q  = frsq(l2);
  const float hx = q*Px, hy = q*Py, hz = q*Pz;
  const float s2 = fmaxf(hy*hy + hz*hz, 1e-12f);
  const float ist = frsq(s2);
  const float st  = s2 * ist;
  X.f[0]=hx;        X.f[1]=hy;          X.f[2]=hz;
  X.f[3]=-st;       X.f[4]=hx*hy*ist;   X.f[5]=hx*hz*ist;
  X.f[6]=0.f;       X.f[7]=-hz*ist;     X.f[8]=hy*ist;
  X.f[9]=Px;        X.f[10]=Py;        X.f[11]=Pz;
}

__global__ void __launch_bounds__(256) __attribute__((amdgpu_waves_per_eu(2, 4)))
rmsd_kernel(const float* __restrict__ pred, const float* __restrict__ targ,
            float* __restrict__ out){
  __shared__ float pos[128*25 + 8];   // pitch 25 (coprime w/ 32 banks): 12.8 KB
  __shared__ float Tbuf[2][12];       // per-chain half-0 inclusive totals
  __shared__ float ini[3];            // pred a1x, a2x, a2y
  __shared__ float part;              // targ half-1 reduced partial

  const int row  = blockIdx.x;
  const int tid  = threadIdx.x;
  const int ln   = tid & 63;
  const int wv   = tid >> 6;          // 0..3
  const int c    = wv >> 1;           // 0 = pred, 1 = targ
  const int half = wv & 1;            // which half of the chain
  const int lid  = (half << 6) | ln;  // 0..127 lane-in-chain
  const int j0   = lid * CHUNK;       // first step owned (<= 1016)

  const float* __restrict__ v = (c ? targ : pred) + (size_t)row * LROW;
  const float cl = c ? 1e30f : 1.0f;  // reference clips pred only

  // ---- vectorized batch loads: 9 dwordx4-class + 1 scalar, all in flight ----
  const f4 sc0 = *(const f4*)(v + 2*j0);
  const f4 sc1 = *(const f4*)(v + 2*j0 + 4);
  const f4 sc2 = *(const f4*)(v + 2*j0 + 8);
  const f4 sc3 = *(const f4*)(v + 2*j0 + 12);
  const f4 dd0 = *(const f4*)(v + 2043 + j0);
  const f4 dd1 = *(const f4*)(v + 2047 + j0);
  const f4 bv0 = *(const f4*)(v + 3065 + j0);          // lane127: 4081..4084, in-bounds
  const int  bb  = 3069 + j0;
  const bool cbm = bb > 4083;                          // true only for lane 127
  const f4 bv1 = *(const f4*)(v + (cbm ? 4083 : bb));  // lane127: 4083..4086
  const int  b8i = 3073 + j0;
  const float bv8 = v[b8i > 4086 ? 4086 : b8i];

  // broadcast fold inputs (wave-uniform -> scalar loads)
  const float rb0 = fminf(fmaxf(v[3064], -cl), cl);
  const float rd0 = fminf(fmaxf(v[2042], -cl), cl);
  const float rb1w= fminf(fmaxf(v[3065], -cl), cl);

  // ---- unpack ----
  float s0[CHUNK], s1[CHUNK], dd[CHUNK], bv[CHUNK+1];
  s0[0]=sc0[0]; s1[0]=sc0[1]; s0[1]=sc0[2]; s1[1]=sc0[3];
  s0[2]=sc1[0]; s1[2]=sc1[1]; s0[3]=sc1[2]; s1[3]=sc1[3];
  s0[4]=sc2[0]; s1[4]=sc2[1]; s0[5]=sc2[2]; s1[5]=sc2[3];
  s0[6]=sc3[0]; s1[6]=sc3[1]; s0[7]=sc3[2]; s1[7]=sc3[3];
  dd[0]=dd0[0]; dd[1]=dd0[1]; dd[2]=dd0[2]; dd[3]=dd0[3];
  dd[4]=dd1[0]; dd[5]=dd1[1]; dd[6]=dd1[2]; dd[7]=dd1[3];
  bv[0]=bv0[0]; bv[1]=bv0[1]; bv[2]=bv0[2]; bv[3]=bv0[3];
  bv[4]= cbm ? bv1[2] : bv1[0];      // lane127: v[4085] = elem2 of clamped vec
  bv[5]= cbm ? bv1[3] : bv1[1];      // lane127: v[4086] (its last needed value)
  bv[6]= bv1[2];                     // lane127: finite garbage, steps guarded
  bv[7]= bv1[3];
  bv[8]= bv8;

  // denorm bond lengths once (b2 of step k == b1 of step k+1)
  #pragma unroll
  for (int m = 0; m <= CHUNK; ++m)
    bv[m] = fmaf(fminf(fmaxf(bv[m], -cl), cl), 1.05f, 1.95f);

  // ---- per-step P in lane-local frame ----
  float Px[CHUNK], Py[CHUNK], Pz[CHUNK];
  #pragma unroll
  for (int k = 0; k < CHUNK; ++k){
    const float a0 = fminf(fmaxf(s0[k], -cl), cl);
    const float a1 = fminf(fmaxf(s1[k], -cl), cl);
    const float d  = fmaf(fminf(fmaxf(dd[k], -cl), cl), 1.75f, 3.25f);
    const float b1 = bv[k], b2 = bv[k+1];
    float ct = (b1*b1 + b2*b2 - d*d) * frcp(2.0f*b1*b2);
    ct = fminf(fmaxf(ct, -1.0f + EPSF), 1.0f - EPSF);
    const float st = sqrtf(fmaxf(1.0f - ct*ct, 0.0f));
    const float r2 = a0*a0 + a1*a1;
    const bool ok = r2 > 1e-36f;
    const float ir = ok ? frcp(sqrtf(r2)) : 0.0f;
    const float scv = a0 * ir;
    const float ccv = ok ? a1 * ir : 1.0f;
    Px[k] = -b2 * ct;
    Py[k] = b2 * st * ccv;
    Pz[k] = b2 * st * scv;
  }

  // ---- per-lane chunk compose (8 steps), snapshot local-prefix translations ----
  Xf X;
  float tl[CHUNK][3];
  xinitP(X, Px[0], Py[0], Pz[0]);
  tl[0][0]=X.f[9]; tl[0][1]=X.f[10]; tl[0][2]=X.f[11];
  #pragma unroll
  for (int k = 1; k < CHUNK; ++k){
    if (j0 + k < NSTEP) xstepP(X, Px[k], Py[k], Pz[k]);
    tl[k][0]=X.f[9]; tl[k][1]=X.f[10]; tl[k][2]=X.f[11];
  }

  // ---- in-wave inclusive scan (Hillis-Steele, non-commutative) ----
  #pragma unroll
  for (int off = 1; off < 64; off <<= 1){
    Xf o;
    #pragma unroll
    for (int i = 0; i < 12; ++i) o.f[i] = __shfl_up(X.f[i], off);
    if (ln >= off) X = xcombine(o, X);
  }

  // half-0 publishes its chain-half total for the cross-wave prefix
  if (half == 0 && ln == 63){
    #pragma unroll
    for (int i = 0; i < 12; ++i) Tbuf[c][i] = X.f[i];
  }

  Xf E;
  #pragma unroll
  for (int i = 0; i < 12; ++i) E.f[i] = __shfl_up(X.f[i], 1);
  if (ln == 0) E = xident();

  __syncthreads();   // Tbuf visible

  if (half == 1){    // prepend half-0 total (ln==0: E=ident -> E=T)
    Xf T;
    #pragma unroll
    for (int i = 0; i < 12; ++i) T.f[i] = Tbuf[c][i];
    E = xcombine(T, E);
  }

  // ---- fold (F0, a2): G = F0*E.M ; G.t = a2 + F0*E.t ----
  const float bl0 = fmaf(rb0,  1.05f, 1.95f);
  const float d0  = fmaf(rd0,  1.75f, 3.25f);
  const float b1f = fmaf(rb1w, 1.05f, 1.95f);
  float ct0 = (bl0*bl0 + b1f*b1f - d0*d0) * frcp(2.0f*bl0*b1f);
  ct0 = fminf(fmaxf(ct0, -1.0f + EPSF), 1.0f - EPSF);
  const float st0 = sqrtf(fmaxf(1.0f - ct0*ct0, 0.0f));
  const float a1x = bl0;
  const float a2x = bl0 - b1f*ct0;
  const float a2y = b1f*st0;

  Xf G;   // F0 rows: (-ct0,-st0,0),(st0,-ct0,0),(0,0,1) applied to each column + t
  #pragma unroll
  for (int c3 = 0; c3 < 12; c3 += 3){
    const float ex = E.f[c3], ey = E.f[c3+1], ez = E.f[c3+2];
    G.f[c3]   = -ct0*ex - st0*ey;
    G.f[c3+1] =  st0*ex - ct0*ey;
    G.f[c3+2] =  ez;
  }
  G.f[9] += a2x; G.f[10] += a2y;

  // ---- positions p_k = G.t + G.M * tl[k]  (in place) ----
  #pragma unroll
  for (int k = 0; k < CHUNK; ++k){
    const float tx = tl[k][0], ty = tl[k][1], tz = tl[k][2];
    tl[k][0] = G.f[9]  + G.f[0]*tx + G.f[3]*ty + G.f[6]*tz;
    tl[k][1] = G.f[10] + G.f[1]*tx + G.f[4]*ty + G.f[7]*tz;
    tl[k][2] = G.f[11] + G.f[2]*tx + G.f[5]*ty + G.f[8]*tz;
  }

  // ---- pred publishes positions (pitch 25 -> conflict-free) ----
  if (c == 0){
    #pragma unroll
    for (int k = 0; k < CHUNK; ++k){
      if (j0 + k < NSTEP){
        const int o = lid*25 + 3*k;
        pos[o] = tl[k][0]; pos[o+1] = tl[k][1]; pos[o+2] = tl[k][2];
      }
    }
    if (lid == 0){ ini[0] = a1x; ini[1] = a2x; ini[2] = a2y; }
  }
  __syncthreads();

  // ---- targ waves: diff + reduce ----
  float acc = 0.0f;
  if (c == 1){
    if (lid == 0){
      const float dx = ini[0] - a1x;   // a1 differs only in x; a0 diff = 0
      const float dy = ini[1] - a2x;   // a2 differs in x,y (z = 0)
      const float dz = ini[2] - a2y;
      acc = dx*dx + dy*dy + dz*dz;
    }
    #pragma unroll
    for (int k = 0; k < CHUNK; ++k){
      if (j0 + k < NSTEP){
        const int o = lid*25 + 3*k;
        const float dx = pos[o]   - tl[k][0];
        const float dy = pos[o+1] - tl[k][1];
        const float dz = pos[o+2] - tl[k][2];
        acc = fmaf(dx, dx, acc);
        acc = fmaf(dy, dy, acc);
        acc = fmaf(dz, dz, acc);
      }
    }
    #pragma unroll
    for (int off = 32; off > 0; off >>= 1) acc += __shfl_down(acc, off);
    if (half == 1 && ln == 0) part = acc;   // wv3 partial
  }
  __syncthreads();
  if (wv == 2 && ln == 0) atomicAdd(out, (acc + part) * INVMEAN);  // 1 atomic/block
}

extern "C" void kernel_launch(void* const* d_in, const int* in_sizes, int n_in,
                              void* d_out, int out_size, void* d_ws, size_t ws_size,
                              hipStream_t stream) {
  const float* pred = (const float*)d_in[0];
  const float* targ = (const float*)d_in[1];
  float* out = (float*)d_out;

  hipMemsetAsync(d_out, 0, sizeof(float), stream);
  rmsd_kernel<<<NROW, 256, 0, stream>>>(pred, targ, out);
}